// Round 3
// baseline (789.789 us; speedup 1.0000x reference)
//
#include <hip/hip_runtime.h>
#include <cstdint>

#define NN 50000
#define NE 600000
#define NGR 256
#define HD 128
#define BN_EPS 1e-5f

// ---------------- zero scratch accumulators ----------------
__global__ void k_zero(float4* __restrict__ p, int n4) {
  int i = blockIdx.x * blockDim.x + threadIdx.x;
  if (i < n4) p[i] = make_float4(0.f, 0.f, 0.f, 0.f);
}

// ---------------- in-degree count ----------------
__global__ void k_count(const int* __restrict__ dst, int* __restrict__ cnt) {
  int i = blockIdx.x * blockDim.x + threadIdx.x;
  if (i < NE) atomicAdd(&cnt[dst[i]], 1);
}

// ---------------- CSR row-ptr scan (3 phases) ----------------
__global__ __launch_bounds__(1024) void k_scan1(const int* __restrict__ cnt,
                                                int* __restrict__ rowptr,
                                                int* __restrict__ aux,
                                                float* __restrict__ dis) {
  __shared__ int sd[1024];
  int tid = threadIdx.x;
  int i = blockIdx.x * 1024 + tid;
  int v = (i < NN) ? cnt[i] : 0;
  if (i < NN) dis[i] = 1.0f / sqrtf((float)v + 1.0f);  // deg^{-1/2}, deg = in-deg + self-loop
  sd[tid] = v;
  __syncthreads();
  for (int off = 1; off < 1024; off <<= 1) {
    int t = (tid >= off) ? sd[tid - off] : 0;
    __syncthreads();
    sd[tid] += t;
    __syncthreads();
  }
  if (i < NN) rowptr[i + 1] = sd[tid];
  if (tid == 1023) aux[blockIdx.x] = sd[1023];
}

__global__ void k_scan2(const int* __restrict__ aux, int* __restrict__ auxsc, int nchunks) {
  if (threadIdx.x == 0 && blockIdx.x == 0) {
    int run = 0;
    for (int c = 0; c < nchunks; ++c) { auxsc[c] = run; run += aux[c]; }
  }
}

__global__ void k_scan3(int* __restrict__ rowptr, const int* __restrict__ auxsc) {
  int i = blockIdx.x * blockDim.x + threadIdx.x;
  if (i < NN) rowptr[i + 1] += auxsc[i >> 10];
  if (i == 0) rowptr[0] = 0;
}

__global__ void k_fill(const int* __restrict__ src, const int* __restrict__ dst,
                       const int* __restrict__ rowptr, int* __restrict__ fillp,
                       int* __restrict__ colidx) {
  int i = blockIdx.x * blockDim.x + threadIdx.x;
  if (i < NE) {
    int d = dst[i];
    int p = rowptr[d] + atomicAdd(&fillp[d], 1);
    colidx[p] = src[i];
  }
}

// ---------------- GEMM: HS = dis * (act(X) @ W) ----------------
// act = identity (layer 1) or relu(scale*x + shift)  (fused BN+ReLU of prev layer)
// Block: 256 threads, tile 64 rows x 128 cols, thread computes 4 rows x 8 cols.
template<bool BN>
__global__ __launch_bounds__(256) void k_gemm(
    const float* __restrict__ X, const float* __restrict__ W,
    const float* __restrict__ scale, const float* __restrict__ shift,
    const float* __restrict__ dis, float* __restrict__ HS) {
  __shared__ float xt[64][36];    // stride 36: av reads land banks {k,k+16} -> 2-way alias (free)
  __shared__ float wt[32][132];   // stride 132: 16 float2 addrs cover all 32 banks -> conflict-free
  int tid = threadIdx.x;
  int tc = tid & 15;
  int tr = tid >> 4;
  int row0 = blockIdx.x * 64;
  int r0 = tr * 4;
  float acc[4][8];
#pragma unroll
  for (int i = 0; i < 4; ++i)
#pragma unroll
    for (int j = 0; j < 8; ++j) acc[i][j] = 0.f;

  int lr = tid >> 2;          // 0..63  (x-tile row)
  int lk = (tid & 3) * 8;     // 0,8,16,24
  int wk = tid >> 3;          // 0..31  (w-tile k)
  int wc = (tid & 7) * 16;    // 0..112

  for (int kk = 0; kk < HD; kk += 32) {
    float4 a0 = make_float4(0.f, 0.f, 0.f, 0.f);
    float4 a1 = make_float4(0.f, 0.f, 0.f, 0.f);
    int row = row0 + lr;
    if (row < NN) {
      const float* xp = &X[(size_t)row * HD + kk + lk];
      a0 = *(const float4*)xp;
      a1 = *(const float4*)(xp + 4);
    }
    if constexpr (BN) {
      float4 sc0 = *(const float4*)&scale[kk + lk];
      float4 sc1 = *(const float4*)&scale[kk + lk + 4];
      float4 sh0 = *(const float4*)&shift[kk + lk];
      float4 sh1 = *(const float4*)&shift[kk + lk + 4];
      a0.x = fmaxf(fmaf(sc0.x, a0.x, sh0.x), 0.f);
      a0.y = fmaxf(fmaf(sc0.y, a0.y, sh0.y), 0.f);
      a0.z = fmaxf(fmaf(sc0.z, a0.z, sh0.z), 0.f);
      a0.w = fmaxf(fmaf(sc0.w, a0.w, sh0.w), 0.f);
      a1.x = fmaxf(fmaf(sc1.x, a1.x, sh1.x), 0.f);
      a1.y = fmaxf(fmaf(sc1.y, a1.y, sh1.y), 0.f);
      a1.z = fmaxf(fmaf(sc1.z, a1.z, sh1.z), 0.f);
      a1.w = fmaxf(fmaf(sc1.w, a1.w, sh1.w), 0.f);
    }
    *(float4*)&xt[lr][lk] = a0;
    *(float4*)&xt[lr][lk + 4] = a1;
    const float* wp = &W[(size_t)(kk + wk) * HD + wc];
    *(float4*)&wt[wk][wc]      = *(const float4*)(wp);
    *(float4*)&wt[wk][wc + 4]  = *(const float4*)(wp + 4);
    *(float4*)&wt[wk][wc + 8]  = *(const float4*)(wp + 8);
    *(float4*)&wt[wk][wc + 12] = *(const float4*)(wp + 12);
    __syncthreads();
#pragma unroll 4
    for (int k = 0; k < 32; ++k) {
      float av[4];
#pragma unroll
      for (int i = 0; i < 4; ++i) av[i] = xt[r0 + i][k];
      float2 bv[4];
#pragma unroll
      for (int j = 0; j < 4; ++j) bv[j] = *(const float2*)&wt[k][tc * 2 + 32 * j];
#pragma unroll
      for (int i = 0; i < 4; ++i)
#pragma unroll
        for (int j = 0; j < 4; ++j) {
          acc[i][2 * j]     = fmaf(av[i], bv[j].x, acc[i][2 * j]);
          acc[i][2 * j + 1] = fmaf(av[i], bv[j].y, acc[i][2 * j + 1]);
        }
    }
    __syncthreads();
  }
#pragma unroll
  for (int i = 0; i < 4; ++i) {
    int row = row0 + r0 + i;
    if (row < NN) {
      float dv = dis[row];
#pragma unroll
      for (int j = 0; j < 4; ++j) {
        float2 st = make_float2(acc[i][2 * j] * dv, acc[i][2 * j + 1] * dv);
        *(float2*)&HS[(size_t)row * HD + tc * 2 + 32 * j] = st;
      }
    }
  }
}

// ---------------- aggregation (CSR gather) ----------------
// MODE 0: AGG[i] = dis[i]*(sum_{e in row i} HS[src] + HS[i]) + b ; accumulate BN stats
// MODE 1: v = relu(same); per-node scalar dot(v, Wl) atomically pooled per graph
template<int MODE>
__global__ __launch_bounds__(256) void k_agg(
    const float* __restrict__ HS, const float* __restrict__ dis,
    const int* __restrict__ rowptr, const int* __restrict__ colidx,
    const float* __restrict__ bias,
    float* __restrict__ AGG, float* __restrict__ stats,
    const int* __restrict__ batch, const float* __restrict__ Wl,
    float* __restrict__ gsum, float* __restrict__ gcnt) {
  __shared__ float red[4][128];
  int tid = threadIdx.x;
  int lane = tid & 63;
  int wv = tid >> 6;        // wave id 0..3, one node per wave per iter
  int c0 = lane * 2;        // this lane's two channels
  float b0 = bias[c0], b1 = bias[c0 + 1];
  float wl0 = 0.f, wl1 = 0.f;
  if (MODE == 1) { wl0 = Wl[c0]; wl1 = Wl[c0 + 1]; }
  float ssum0 = 0.f, ssum1 = 0.f, ssq0 = 0.f, ssq1 = 0.f;
  int stride = gridDim.x * 4;
  for (int i = blockIdx.x * 4 + wv; i < NN; i += stride) {
    float2 self = *(const float2*)&HS[(size_t)i * HD + c0];
    float ax = self.x, ay = self.y;   // self-loop term (HS pre-scaled by dis)
    float bx = 0.f, by = 0.f;         // second chain for latency overlap
    int e0 = rowptr[i], e1 = rowptr[i + 1];
    int e = e0;
    // 4-edge unroll: 4 loads in flight before first consume (MLP for L3-latency-bound gather)
    for (; e + 3 < e1; e += 4) {
      int s0 = colidx[e];
      int s1 = colidx[e + 1];
      int s2 = colidx[e + 2];
      int s3 = colidx[e + 3];
      float2 h0 = *(const float2*)&HS[(size_t)s0 * HD + c0];
      float2 h1 = *(const float2*)&HS[(size_t)s1 * HD + c0];
      float2 h2 = *(const float2*)&HS[(size_t)s2 * HD + c0];
      float2 h3 = *(const float2*)&HS[(size_t)s3 * HD + c0];
      ax += h0.x; ay += h0.y;
      bx += h1.x; by += h1.y;
      ax += h2.x; ay += h2.y;
      bx += h3.x; by += h3.y;
    }
    for (; e < e1; ++e) {
      int s0 = colidx[e];
      float2 h0 = *(const float2*)&HS[(size_t)s0 * HD + c0];
      ax += h0.x; ay += h0.y;
    }
    float di = dis[i];
    float vx = fmaf(di, ax + bx, b0);
    float vy = fmaf(di, ay + by, b1);
    if (MODE == 0) {
      *(float2*)&AGG[(size_t)i * HD + c0] = make_float2(vx, vy);
      ssum0 += vx; ssum1 += vy;
      ssq0 = fmaf(vx, vx, ssq0);
      ssq1 = fmaf(vy, vy, ssq1);
    } else {
      vx = fmaxf(vx, 0.f);
      vy = fmaxf(vy, 0.f);
      float p = vx * wl0 + vy * wl1;
#pragma unroll
      for (int m = 32; m >= 1; m >>= 1) p += __shfl_xor(p, m);
      if (lane == 0) {
        int b = batch[i];
        atomicAdd(&gsum[b], p);
        atomicAdd(&gcnt[b], 1.0f);
      }
    }
  }
  if (MODE == 0) {
    red[wv][c0] = ssum0; red[wv][c0 + 1] = ssum1;
    __syncthreads();
    if (wv == 0) {
      float t0 = red[0][c0] + red[1][c0] + red[2][c0] + red[3][c0];
      float t1 = red[0][c0 + 1] + red[1][c0 + 1] + red[2][c0 + 1] + red[3][c0 + 1];
      atomicAdd(&stats[c0], t0);
      atomicAdd(&stats[c0 + 1], t1);
    }
    __syncthreads();
    red[wv][c0] = ssq0; red[wv][c0 + 1] = ssq1;
    __syncthreads();
    if (wv == 0) {
      float q0 = red[0][c0] + red[1][c0] + red[2][c0] + red[3][c0];
      float q1 = red[0][c0 + 1] + red[1][c0 + 1] + red[2][c0 + 1] + red[3][c0 + 1];
      atomicAdd(&stats[HD + c0], q0);
      atomicAdd(&stats[HD + c0 + 1], q1);
    }
  }
}

// ---------------- BN finalize: per-channel scale/shift ----------------
__global__ void k_bnfin(const float* __restrict__ stats, const float* __restrict__ gamma,
                        const float* __restrict__ beta, float* __restrict__ scale,
                        float* __restrict__ shift) {
  int c = threadIdx.x;
  float inv_n = 1.0f / (float)NN;
  float mean = stats[c] * inv_n;
  float var = stats[HD + c] * inv_n - mean * mean;
  float s = gamma[c] / sqrtf(var + BN_EPS);
  scale[c] = s;
  shift[c] = fmaf(-mean, s, beta[c]);
}

// ---------------- final: mean-pool divide + bias ----------------
__global__ void k_final(const float* __restrict__ gsum, const float* __restrict__ gcnt,
                        const float* __restrict__ bl, float* __restrict__ out) {
  int g = threadIdx.x;
  out[g] = gsum[g] / fmaxf(gcnt[g], 1.0f) + bl[0];
}

extern "C" void kernel_launch(void* const* d_in, const int* in_sizes, int n_in,
                              void* d_out, int out_size, void* d_ws, size_t ws_size,
                              hipStream_t stream) {
  (void)in_sizes; (void)n_in; (void)out_size; (void)ws_size;
  const float* x   = (const float*)d_in[0];
  const int* ei    = (const int*)d_in[1];
  const int* batch = (const int*)d_in[2];
  const float* W1  = (const float*)d_in[3];
  const float* b1  = (const float*)d_in[4];
  const float* g1  = (const float*)d_in[5];
  const float* be1 = (const float*)d_in[6];
  const float* W2  = (const float*)d_in[7];
  const float* b2  = (const float*)d_in[8];
  const float* g2  = (const float*)d_in[9];
  const float* be2 = (const float*)d_in[10];
  const float* W3  = (const float*)d_in[11];
  const float* b3  = (const float*)d_in[12];
  const float* Wl  = (const float*)d_in[13];
  const float* bl  = (const float*)d_in[14];
  float* out = (float*)d_out;

  const int* srcv = ei;        // edge_index[0]
  const int* dstv = ei + NE;   // edge_index[1]

  // ---- workspace layout (all offsets 16B-aligned) ----
  float* hs     = (float*)d_ws;             // [NN][HD]
  float* agg    = hs + (size_t)NN * HD;     // [NN][HD]
  float* dis    = agg + (size_t)NN * HD;    // [NN]
  int*   rowptr = (int*)(dis + NN);         // [NN+1] (padded to NN+4)
  int*   colidx = rowptr + (NN + 4);        // [NE]
  float* scale1 = (float*)(colidx + NE);
  float* shift1 = scale1 + HD;
  float* scale2 = shift1 + HD;
  float* shift2 = scale2 + HD;
  float* zbase  = shift2 + HD;              // ---- zeroed region start ----
  int*   degc   = (int*)zbase;              // [NN]
  int*   fillp  = degc + NN;                // [NN]
  int*   aux    = fillp + NN;               // [64]
  int*   auxsc  = aux + 64;                 // [64]
  float* stats1 = (float*)(auxsc + 64);     // [256]
  float* stats2 = stats1 + 2 * HD;          // [256]
  float* gsum   = stats2 + 2 * HD;          // [256]
  float* gcnt   = gsum + NGR;               // [256]
  float* zend   = gcnt + NGR;
  int n4 = (int)(((char*)zend - (char*)zbase) / 16);

  k_zero<<<(n4 + 255) / 256, 256, 0, stream>>>((float4*)zbase, n4);

  // CSR build (once; reused by all 3 layers)
  k_count<<<(NE + 255) / 256, 256, 0, stream>>>(dstv, degc);
  int nchunk = (NN + 1023) / 1024;
  k_scan1<<<nchunk, 1024, 0, stream>>>(degc, rowptr, aux, dis);
  k_scan2<<<1, 1, 0, stream>>>(aux, auxsc, nchunk);
  k_scan3<<<(NN + 255) / 256, 256, 0, stream>>>(rowptr, auxsc);
  k_fill<<<(NE + 255) / 256, 256, 0, stream>>>(srcv, dstv, rowptr, fillp, colidx);

  int gblk = (NN + 63) / 64;
  // layer 1
  k_gemm<false><<<gblk, 256, 0, stream>>>(x, W1, nullptr, nullptr, dis, hs);
  k_agg<0><<<2048, 256, 0, stream>>>(hs, dis, rowptr, colidx, b1, agg, stats1,
                                     nullptr, nullptr, nullptr, nullptr);
  k_bnfin<<<1, HD, 0, stream>>>(stats1, g1, be1, scale1, shift1);
  // layer 2
  k_gemm<true><<<gblk, 256, 0, stream>>>(agg, W2, scale1, shift1, dis, hs);
  k_agg<0><<<2048, 256, 0, stream>>>(hs, dis, rowptr, colidx, b2, agg, stats2,
                                     nullptr, nullptr, nullptr, nullptr);
  k_bnfin<<<1, HD, 0, stream>>>(stats2, g2, be2, scale2, shift2);
  // layer 3 (BN+ReLU of layer2 fused into GEMM load; pool+linear fused into agg)
  k_gemm<true><<<gblk, 256, 0, stream>>>(agg, W3, scale2, shift2, dis, hs);
  k_agg<1><<<2048, 256, 0, stream>>>(hs, dis, rowptr, colidx, b3, nullptr, nullptr,
                                     batch, Wl, gsum, gcnt);
  k_final<<<1, NGR, 0, stream>>>(gsum, gcnt, bl, out);
}

// Round 4
// 731.991 us; speedup vs baseline: 1.0790x; 1.0790x over previous
//
#include <hip/hip_runtime.h>
#include <cstdint>

#define NN 50000
#define NE 600000
#define NGR 256
#define HD 128
#define HD2 64            // bf16x2 packed channels per row
#define BN_EPS 1e-5f

// ---- bf16 pack/unpack (bit ops; values are normal floats, no inf/nan) ----
static __device__ __forceinline__ unsigned f2bf(float f) {
  unsigned u = __float_as_uint(f);
  return (u + 0x7FFFu + ((u >> 16) & 1u)) >> 16;   // round-to-nearest-even
}
static __device__ __forceinline__ float bf_lo(unsigned v) {
  return __uint_as_float(v << 16);
}
static __device__ __forceinline__ float bf_hi(unsigned v) {
  return __uint_as_float(v & 0xFFFF0000u);
}

// ---------------- zero scratch accumulators ----------------
__global__ void k_zero(float4* __restrict__ p, int n4) {
  int i = blockIdx.x * blockDim.x + threadIdx.x;
  if (i < n4) p[i] = make_float4(0.f, 0.f, 0.f, 0.f);
}

// ---------------- in-degree count ----------------
__global__ void k_count(const int* __restrict__ dst, int* __restrict__ cnt) {
  int i = blockIdx.x * blockDim.x + threadIdx.x;
  if (i < NE) atomicAdd(&cnt[dst[i]], 1);
}

// ---------------- CSR row-ptr scan (3 phases) ----------------
__global__ __launch_bounds__(1024) void k_scan1(const int* __restrict__ cnt,
                                                int* __restrict__ rowptr,
                                                int* __restrict__ aux,
                                                float* __restrict__ dis) {
  __shared__ int sd[1024];
  int tid = threadIdx.x;
  int i = blockIdx.x * 1024 + tid;
  int v = (i < NN) ? cnt[i] : 0;
  if (i < NN) dis[i] = 1.0f / sqrtf((float)v + 1.0f);
  sd[tid] = v;
  __syncthreads();
  for (int off = 1; off < 1024; off <<= 1) {
    int t = (tid >= off) ? sd[tid - off] : 0;
    __syncthreads();
    sd[tid] += t;
    __syncthreads();
  }
  if (i < NN) rowptr[i + 1] = sd[tid];
  if (tid == 1023) aux[blockIdx.x] = sd[1023];
}

__global__ void k_scan2(const int* __restrict__ aux, int* __restrict__ auxsc, int nchunks) {
  if (threadIdx.x == 0 && blockIdx.x == 0) {
    int run = 0;
    for (int c = 0; c < nchunks; ++c) { auxsc[c] = run; run += aux[c]; }
  }
}

__global__ void k_scan3(int* __restrict__ rowptr, const int* __restrict__ auxsc) {
  int i = blockIdx.x * blockDim.x + threadIdx.x;
  if (i < NN) rowptr[i + 1] += auxsc[i >> 10];
  if (i == 0) rowptr[0] = 0;
}

__global__ void k_fill(const int* __restrict__ src, const int* __restrict__ dst,
                       const int* __restrict__ rowptr, int* __restrict__ fillp,
                       int* __restrict__ colidx) {
  int i = blockIdx.x * blockDim.x + threadIdx.x;
  if (i < NE) {
    int d = dst[i];
    int p = rowptr[d] + atomicAdd(&fillp[d], 1);
    colidx[p] = src[i];
  }
}

// ---------------- GEMM: HS(bf16x2) = dis * (act(X) @ W) ----------------
// act = identity (layer 1) or relu(scale*x + shift)  (fused BN+ReLU of prev layer)
// X stays fp32; only the gather operand HS is packed to bf16.
template<bool BN>
__global__ __launch_bounds__(256) void k_gemm(
    const float* __restrict__ X, const float* __restrict__ W,
    const float* __restrict__ scale, const float* __restrict__ shift,
    const float* __restrict__ dis, unsigned* __restrict__ HS) {
  __shared__ float xt[64][36];    // stride 36: av reads land banks {k,k+16} -> 2-way alias (free)
  __shared__ float wt[32][132];   // stride 132: 16 float2 addrs cover all 32 banks -> conflict-free
  int tid = threadIdx.x;
  int tc = tid & 15;
  int tr = tid >> 4;
  int row0 = blockIdx.x * 64;
  int r0 = tr * 4;
  float acc[4][8];
#pragma unroll
  for (int i = 0; i < 4; ++i)
#pragma unroll
    for (int j = 0; j < 8; ++j) acc[i][j] = 0.f;

  int lr = tid >> 2;          // 0..63  (x-tile row)
  int lk = (tid & 3) * 8;     // 0,8,16,24
  int wk = tid >> 3;          // 0..31  (w-tile k)
  int wc = (tid & 7) * 16;    // 0..112

  for (int kk = 0; kk < HD; kk += 32) {
    float4 a0 = make_float4(0.f, 0.f, 0.f, 0.f);
    float4 a1 = make_float4(0.f, 0.f, 0.f, 0.f);
    int row = row0 + lr;
    if (row < NN) {
      const float* xp = &X[(size_t)row * HD + kk + lk];
      a0 = *(const float4*)xp;
      a1 = *(const float4*)(xp + 4);
    }
    if constexpr (BN) {
      float4 sc0 = *(const float4*)&scale[kk + lk];
      float4 sc1 = *(const float4*)&scale[kk + lk + 4];
      float4 sh0 = *(const float4*)&shift[kk + lk];
      float4 sh1 = *(const float4*)&shift[kk + lk + 4];
      a0.x = fmaxf(fmaf(sc0.x, a0.x, sh0.x), 0.f);
      a0.y = fmaxf(fmaf(sc0.y, a0.y, sh0.y), 0.f);
      a0.z = fmaxf(fmaf(sc0.z, a0.z, sh0.z), 0.f);
      a0.w = fmaxf(fmaf(sc0.w, a0.w, sh0.w), 0.f);
      a1.x = fmaxf(fmaf(sc1.x, a1.x, sh1.x), 0.f);
      a1.y = fmaxf(fmaf(sc1.y, a1.y, sh1.y), 0.f);
      a1.z = fmaxf(fmaf(sc1.z, a1.z, sh1.z), 0.f);
      a1.w = fmaxf(fmaf(sc1.w, a1.w, sh1.w), 0.f);
    }
    *(float4*)&xt[lr][lk] = a0;
    *(float4*)&xt[lr][lk + 4] = a1;
    const float* wp = &W[(size_t)(kk + wk) * HD + wc];
    *(float4*)&wt[wk][wc]      = *(const float4*)(wp);
    *(float4*)&wt[wk][wc + 4]  = *(const float4*)(wp + 4);
    *(float4*)&wt[wk][wc + 8]  = *(const float4*)(wp + 8);
    *(float4*)&wt[wk][wc + 12] = *(const float4*)(wp + 12);
    __syncthreads();
#pragma unroll 4
    for (int k = 0; k < 32; ++k) {
      float av[4];
#pragma unroll
      for (int i = 0; i < 4; ++i) av[i] = xt[r0 + i][k];
      float2 bv[4];
#pragma unroll
      for (int j = 0; j < 4; ++j) bv[j] = *(const float2*)&wt[k][tc * 2 + 32 * j];
#pragma unroll
      for (int i = 0; i < 4; ++i)
#pragma unroll
        for (int j = 0; j < 4; ++j) {
          acc[i][2 * j]     = fmaf(av[i], bv[j].x, acc[i][2 * j]);
          acc[i][2 * j + 1] = fmaf(av[i], bv[j].y, acc[i][2 * j + 1]);
        }
    }
    __syncthreads();
  }
#pragma unroll
  for (int i = 0; i < 4; ++i) {
    int row = row0 + r0 + i;
    if (row < NN) {
      float dv = dis[row];
#pragma unroll
      for (int j = 0; j < 4; ++j) {
        // channels (tc*2+32j, tc*2+32j+1) -> packed index tc + 16j
        unsigned p = (f2bf(acc[i][2 * j + 1] * dv) << 16) | f2bf(acc[i][2 * j] * dv);
        HS[(size_t)row * HD2 + tc + 16 * j] = p;
      }
    }
  }
}

// ---------------- aggregation (CSR gather, bf16x2 rows) ----------------
// MODE 0: AGG[i] = dis[i]*(sum_{e in row i} HS[src] + HS[i]) + b ; accumulate BN stats
// MODE 1: v = relu(same); per-node scalar dot(v, Wl) atomically pooled per graph
template<int MODE>
__global__ __launch_bounds__(256) void k_agg(
    const unsigned* __restrict__ HS, const float* __restrict__ dis,
    const int* __restrict__ rowptr, const int* __restrict__ colidx,
    const float* __restrict__ bias,
    float* __restrict__ AGG, float* __restrict__ stats,
    const int* __restrict__ batch, const float* __restrict__ Wl,
    float* __restrict__ gsum, float* __restrict__ gcnt) {
  __shared__ float red[4][128];
  int tid = threadIdx.x;
  int lane = tid & 63;
  int wv = tid >> 6;        // wave id 0..3, one node per wave per iter
  int c0 = lane * 2;        // this lane's two channels (one packed word)
  float b0 = bias[c0], b1 = bias[c0 + 1];
  float wl0 = 0.f, wl1 = 0.f;
  if (MODE == 1) { wl0 = Wl[c0]; wl1 = Wl[c0 + 1]; }
  float ssum0 = 0.f, ssum1 = 0.f, ssq0 = 0.f, ssq1 = 0.f;
  int stride = gridDim.x * 4;
  for (int i = blockIdx.x * 4 + wv; i < NN; i += stride) {
    unsigned sv = HS[(size_t)i * HD2 + lane];
    float ax = bf_lo(sv), ay = bf_hi(sv);  // self-loop term (HS pre-scaled by dis)
    float bx = 0.f, by = 0.f;              // second chain for latency overlap
    int e0 = rowptr[i], e1 = rowptr[i + 1];
    int e = e0;
    // 4-edge unroll: 4 loads in flight before first consume
    for (; e + 3 < e1; e += 4) {
      int s0 = colidx[e];
      int s1 = colidx[e + 1];
      int s2 = colidx[e + 2];
      int s3 = colidx[e + 3];
      unsigned h0 = HS[(size_t)s0 * HD2 + lane];
      unsigned h1 = HS[(size_t)s1 * HD2 + lane];
      unsigned h2 = HS[(size_t)s2 * HD2 + lane];
      unsigned h3 = HS[(size_t)s3 * HD2 + lane];
      ax += bf_lo(h0); ay += bf_hi(h0);
      bx += bf_lo(h1); by += bf_hi(h1);
      ax += bf_lo(h2); ay += bf_hi(h2);
      bx += bf_lo(h3); by += bf_hi(h3);
    }
    for (; e < e1; ++e) {
      int s0 = colidx[e];
      unsigned h0 = HS[(size_t)s0 * HD2 + lane];
      ax += bf_lo(h0); ay += bf_hi(h0);
    }
    float di = dis[i];
    float vx = fmaf(di, ax + bx, b0);
    float vy = fmaf(di, ay + by, b1);
    if (MODE == 0) {
      *(float2*)&AGG[(size_t)i * HD + c0] = make_float2(vx, vy);
      ssum0 += vx; ssum1 += vy;
      ssq0 = fmaf(vx, vx, ssq0);
      ssq1 = fmaf(vy, vy, ssq1);
    } else {
      vx = fmaxf(vx, 0.f);
      vy = fmaxf(vy, 0.f);
      float p = vx * wl0 + vy * wl1;
#pragma unroll
      for (int m = 32; m >= 1; m >>= 1) p += __shfl_xor(p, m);
      if (lane == 0) {
        int b = batch[i];
        atomicAdd(&gsum[b], p);
        atomicAdd(&gcnt[b], 1.0f);
      }
    }
  }
  if (MODE == 0) {
    red[wv][c0] = ssum0; red[wv][c0 + 1] = ssum1;
    __syncthreads();
    if (wv == 0) {
      float t0 = red[0][c0] + red[1][c0] + red[2][c0] + red[3][c0];
      float t1 = red[0][c0 + 1] + red[1][c0 + 1] + red[2][c0 + 1] + red[3][c0 + 1];
      atomicAdd(&stats[c0], t0);
      atomicAdd(&stats[c0 + 1], t1);
    }
    __syncthreads();
    red[wv][c0] = ssq0; red[wv][c0 + 1] = ssq1;
    __syncthreads();
    if (wv == 0) {
      float q0 = red[0][c0] + red[1][c0] + red[2][c0] + red[3][c0];
      float q1 = red[0][c0 + 1] + red[1][c0 + 1] + red[2][c0 + 1] + red[3][c0 + 1];
      atomicAdd(&stats[HD + c0], q0);
      atomicAdd(&stats[HD + c0 + 1], q1);
    }
  }
}

// ---------------- BN finalize: per-channel scale/shift ----------------
__global__ void k_bnfin(const float* __restrict__ stats, const float* __restrict__ gamma,
                        const float* __restrict__ beta, float* __restrict__ scale,
                        float* __restrict__ shift) {
  int c = threadIdx.x;
  float inv_n = 1.0f / (float)NN;
  float mean = stats[c] * inv_n;
  float var = stats[HD + c] * inv_n - mean * mean;
  float s = gamma[c] / sqrtf(var + BN_EPS);
  scale[c] = s;
  shift[c] = fmaf(-mean, s, beta[c]);
}

// ---------------- final: mean-pool divide + bias ----------------
__global__ void k_final(const float* __restrict__ gsum, const float* __restrict__ gcnt,
                        const float* __restrict__ bl, float* __restrict__ out) {
  int g = threadIdx.x;
  out[g] = gsum[g] / fmaxf(gcnt[g], 1.0f) + bl[0];
}

extern "C" void kernel_launch(void* const* d_in, const int* in_sizes, int n_in,
                              void* d_out, int out_size, void* d_ws, size_t ws_size,
                              hipStream_t stream) {
  (void)in_sizes; (void)n_in; (void)out_size; (void)ws_size;
  const float* x   = (const float*)d_in[0];
  const int* ei    = (const int*)d_in[1];
  const int* batch = (const int*)d_in[2];
  const float* W1  = (const float*)d_in[3];
  const float* b1  = (const float*)d_in[4];
  const float* g1  = (const float*)d_in[5];
  const float* be1 = (const float*)d_in[6];
  const float* W2  = (const float*)d_in[7];
  const float* b2  = (const float*)d_in[8];
  const float* g2  = (const float*)d_in[9];
  const float* be2 = (const float*)d_in[10];
  const float* W3  = (const float*)d_in[11];
  const float* b3  = (const float*)d_in[12];
  const float* Wl  = (const float*)d_in[13];
  const float* bl  = (const float*)d_in[14];
  float* out = (float*)d_out;

  const int* srcv = ei;        // edge_index[0]
  const int* dstv = ei + NE;   // edge_index[1]

  // ---- workspace layout (all offsets 16B-aligned) ----
  unsigned* hs  = (unsigned*)d_ws;            // [NN][HD2] bf16x2 packed
  float* agg    = (float*)(hs + (size_t)NN * HD2);  // [NN][HD] fp32
  float* dis    = agg + (size_t)NN * HD;      // [NN]
  int*   rowptr = (int*)(dis + NN);           // [NN+1] (padded to NN+4)
  int*   colidx = rowptr + (NN + 4);          // [NE]
  float* scale1 = (float*)(colidx + NE);
  float* shift1 = scale1 + HD;
  float* scale2 = shift1 + HD;
  float* shift2 = scale2 + HD;
  float* zbase  = shift2 + HD;                // ---- zeroed region start ----
  int*   degc   = (int*)zbase;                // [NN]
  int*   fillp  = degc + NN;                  // [NN]
  int*   aux    = fillp + NN;                 // [64]
  int*   auxsc  = aux + 64;                   // [64]
  float* stats1 = (float*)(auxsc + 64);       // [256]
  float* stats2 = stats1 + 2 * HD;            // [256]
  float* gsum   = stats2 + 2 * HD;            // [256]
  float* gcnt   = gsum + NGR;                 // [256]
  float* zend   = gcnt + NGR;
  int n4 = (int)(((char*)zend - (char*)zbase) / 16);

  k_zero<<<(n4 + 255) / 256, 256, 0, stream>>>((float4*)zbase, n4);

  // CSR build (once; reused by all 3 layers)
  k_count<<<(NE + 255) / 256, 256, 0, stream>>>(dstv, degc);
  int nchunk = (NN + 1023) / 1024;
  k_scan1<<<nchunk, 1024, 0, stream>>>(degc, rowptr, aux, dis);
  k_scan2<<<1, 1, 0, stream>>>(aux, auxsc, nchunk);
  k_scan3<<<(NN + 255) / 256, 256, 0, stream>>>(rowptr, auxsc);
  k_fill<<<(NE + 255) / 256, 256, 0, stream>>>(srcv, dstv, rowptr, fillp, colidx);

  int gblk = (NN + 63) / 64;
  // layer 1
  k_gemm<false><<<gblk, 256, 0, stream>>>(x, W1, nullptr, nullptr, dis, hs);
  k_agg<0><<<2048, 256, 0, stream>>>(hs, dis, rowptr, colidx, b1, agg, stats1,
                                     nullptr, nullptr, nullptr, nullptr);
  k_bnfin<<<1, HD, 0, stream>>>(stats1, g1, be1, scale1, shift1);
  // layer 2
  k_gemm<true><<<gblk, 256, 0, stream>>>(agg, W2, scale1, shift1, dis, hs);
  k_agg<0><<<2048, 256, 0, stream>>>(hs, dis, rowptr, colidx, b2, agg, stats2,
                                     nullptr, nullptr, nullptr, nullptr);
  k_bnfin<<<1, HD, 0, stream>>>(stats2, g2, be2, scale2, shift2);
  // layer 3 (BN+ReLU of layer2 fused into GEMM load; pool+linear fused into agg)
  k_gemm<true><<<gblk, 256, 0, stream>>>(agg, W3, scale2, shift2, dis, hs);
  k_agg<1><<<2048, 256, 0, stream>>>(hs, dis, rowptr, colidx, b3, nullptr, nullptr,
                                     batch, Wl, gsum, gcnt);
  k_final<<<1, NGR, 0, stream>>>(gsum, gcnt, bl, out);
}

// Round 7
// 729.566 us; speedup vs baseline: 1.0825x; 1.0033x over previous
//
#include <hip/hip_runtime.h>
#include <cstdint>

#define NN 50000
#define NE 600000
#define NGR 256
#define HD 128
#define HD2 64            // bf16x2 packed channels per row
#define BN_EPS 1e-5f

// ---- bf16 pack/unpack (bit ops; values are normal floats, no inf/nan) ----
static __device__ __forceinline__ unsigned f2bf(float f) {
  unsigned u = __float_as_uint(f);
  return (u + 0x7FFFu + ((u >> 16) & 1u)) >> 16;   // round-to-nearest-even
}
static __device__ __forceinline__ float bf_lo(unsigned v) {
  return __uint_as_float(v << 16);
}
static __device__ __forceinline__ float bf_hi(unsigned v) {
  return __uint_as_float(v & 0xFFFF0000u);
}

// ---------------- zero scratch accumulators ----------------
__global__ void k_zero(float4* __restrict__ p, int n4) {
  int i = blockIdx.x * blockDim.x + threadIdx.x;
  if (i < n4) p[i] = make_float4(0.f, 0.f, 0.f, 0.f);
}

// ---------------- in-degree count ----------------
__global__ void k_count(const int* __restrict__ dst, int* __restrict__ cnt) {
  int i = blockIdx.x * blockDim.x + threadIdx.x;
  if (i < NE) atomicAdd(&cnt[dst[i]], 1);
}

// ---------------- CSR row-ptr scan (3 phases) ----------------
__global__ __launch_bounds__(1024) void k_scan1(const int* __restrict__ cnt,
                                                int* __restrict__ rowptr,
                                                int* __restrict__ aux,
                                                float* __restrict__ dis) {
  __shared__ int sd[1024];
  int tid = threadIdx.x;
  int i = blockIdx.x * 1024 + tid;
  int v = (i < NN) ? cnt[i] : 0;
  if (i < NN) dis[i] = 1.0f / sqrtf((float)v + 1.0f);
  sd[tid] = v;
  __syncthreads();
  for (int off = 1; off < 1024; off <<= 1) {
    int t = (tid >= off) ? sd[tid - off] : 0;
    __syncthreads();
    sd[tid] += t;
    __syncthreads();
  }
  if (i < NN) rowptr[i + 1] = sd[tid];
  if (tid == 1023) aux[blockIdx.x] = sd[1023];
}

__global__ void k_scan2(const int* __restrict__ aux, int* __restrict__ auxsc, int nchunks) {
  if (threadIdx.x == 0 && blockIdx.x == 0) {
    int run = 0;
    for (int c = 0; c < nchunks; ++c) { auxsc[c] = run; run += aux[c]; }
  }
}

__global__ void k_scan3(int* __restrict__ rowptr, const int* __restrict__ auxsc) {
  int i = blockIdx.x * blockDim.x + threadIdx.x;
  if (i < NN) rowptr[i + 1] += auxsc[i >> 10];
  if (i == 0) rowptr[0] = 0;
}

__global__ void k_fill(const int* __restrict__ src, const int* __restrict__ dst,
                       const int* __restrict__ rowptr, int* __restrict__ fillp,
                       int* __restrict__ colidx) {
  int i = blockIdx.x * blockDim.x + threadIdx.x;
  if (i < NE) {
    int d = dst[i];
    int p = rowptr[d] + atomicAdd(&fillp[d], 1);
    colidx[p] = src[i];
  }
}

// ---------------- GEMM: HS(bf16x2) = dis * (act(X) @ W) ----------------
// act = identity (layer 1) or relu(scale*x + shift)  (fused BN+ReLU of prev layer)
// X stays fp32; only the gather operand HS is packed to bf16.
template<bool BN>
__global__ __launch_bounds__(256) void k_gemm(
    const float* __restrict__ X, const float* __restrict__ W,
    const float* __restrict__ scale, const float* __restrict__ shift,
    const float* __restrict__ dis, unsigned* __restrict__ HS) {
  __shared__ float xt[64][36];    // stride 36: av reads land banks {k,k+16} -> 2-way alias (free)
  __shared__ float wt[32][132];   // stride 132: 16 float2 addrs cover all 32 banks -> conflict-free
  int tid = threadIdx.x;
  int tc = tid & 15;
  int tr = tid >> 4;
  int row0 = blockIdx.x * 64;
  int r0 = tr * 4;
  float acc[4][8];
#pragma unroll
  for (int i = 0; i < 4; ++i)
#pragma unroll
    for (int j = 0; j < 8; ++j) acc[i][j] = 0.f;

  int lr = tid >> 2;          // 0..63  (x-tile row)
  int lk = (tid & 3) * 8;     // 0,8,16,24
  int wk = tid >> 3;          // 0..31  (w-tile k)
  int wc = (tid & 7) * 16;    // 0..112

  for (int kk = 0; kk < HD; kk += 32) {
    float4 a0 = make_float4(0.f, 0.f, 0.f, 0.f);
    float4 a1 = make_float4(0.f, 0.f, 0.f, 0.f);
    int row = row0 + lr;
    if (row < NN) {
      const float* xp = &X[(size_t)row * HD + kk + lk];
      a0 = *(const float4*)xp;
      a1 = *(const float4*)(xp + 4);
    }
    if constexpr (BN) {
      float4 sc0 = *(const float4*)&scale[kk + lk];
      float4 sc1 = *(const float4*)&scale[kk + lk + 4];
      float4 sh0 = *(const float4*)&shift[kk + lk];
      float4 sh1 = *(const float4*)&shift[kk + lk + 4];
      a0.x = fmaxf(fmaf(sc0.x, a0.x, sh0.x), 0.f);
      a0.y = fmaxf(fmaf(sc0.y, a0.y, sh0.y), 0.f);
      a0.z = fmaxf(fmaf(sc0.z, a0.z, sh0.z), 0.f);
      a0.w = fmaxf(fmaf(sc0.w, a0.w, sh0.w), 0.f);
      a1.x = fmaxf(fmaf(sc1.x, a1.x, sh1.x), 0.f);
      a1.y = fmaxf(fmaf(sc1.y, a1.y, sh1.y), 0.f);
      a1.z = fmaxf(fmaf(sc1.z, a1.z, sh1.z), 0.f);
      a1.w = fmaxf(fmaf(sc1.w, a1.w, sh1.w), 0.f);
    }
    *(float4*)&xt[lr][lk] = a0;
    *(float4*)&xt[lr][lk + 4] = a1;
    const float* wp = &W[(size_t)(kk + wk) * HD + wc];
    *(float4*)&wt[wk][wc]      = *(const float4*)(wp);
    *(float4*)&wt[wk][wc + 4]  = *(const float4*)(wp + 4);
    *(float4*)&wt[wk][wc + 8]  = *(const float4*)(wp + 8);
    *(float4*)&wt[wk][wc + 12] = *(const float4*)(wp + 12);
    __syncthreads();
#pragma unroll 4
    for (int k = 0; k < 32; ++k) {
      float av[4];
#pragma unroll
      for (int i = 0; i < 4; ++i) av[i] = xt[r0 + i][k];
      float2 bv[4];
#pragma unroll
      for (int j = 0; j < 4; ++j) bv[j] = *(const float2*)&wt[k][tc * 2 + 32 * j];
#pragma unroll
      for (int i = 0; i < 4; ++i)
#pragma unroll
        for (int j = 0; j < 4; ++j) {
          acc[i][2 * j]     = fmaf(av[i], bv[j].x, acc[i][2 * j]);
          acc[i][2 * j + 1] = fmaf(av[i], bv[j].y, acc[i][2 * j + 1]);
        }
    }
    __syncthreads();
  }
#pragma unroll
  for (int i = 0; i < 4; ++i) {
    int row = row0 + r0 + i;
    if (row < NN) {
      float dv = dis[row];
#pragma unroll
      for (int j = 0; j < 4; ++j) {
        // channels (tc*2+32j, tc*2+32j+1) -> packed index tc + 16j
        unsigned p = (f2bf(acc[i][2 * j + 1] * dv) << 16) | f2bf(acc[i][2 * j] * dv);
        HS[(size_t)row * HD2 + tc + 16 * j] = p;
      }
    }
  }
}

// ---------------- aggregation (CSR gather, bf16x2 rows) ----------------
// MODE 0: AGG[i] = dis[i]*(sum_{e in row i} HS[src] + HS[i]) + b ; accumulate BN stats
// MODE 1: v = relu(same); per-node scalar dot(v, Wl) atomically pooled per graph
// Edge loop unrolled 8-deep (8 independent line fetches in flight per wave):
// the gather is latency/MLP-bound, not byte-bound (round-4 evidence).
template<int MODE>
__global__ __launch_bounds__(256) void k_agg(
    const unsigned* __restrict__ HS, const float* __restrict__ dis,
    const int* __restrict__ rowptr, const int* __restrict__ colidx,
    const float* __restrict__ bias,
    float* __restrict__ AGG, float* __restrict__ stats,
    const int* __restrict__ batch, const float* __restrict__ Wl,
    float* __restrict__ gsum, float* __restrict__ gcnt) {
  __shared__ float red[4][128];
  int tid = threadIdx.x;
  int lane = tid & 63;
  int wv = tid >> 6;        // wave id 0..3, one node per wave per iter
  int c0 = lane * 2;        // this lane's two channels (one packed word)
  float b0 = bias[c0], b1 = bias[c0 + 1];
  float wl0 = 0.f, wl1 = 0.f;
  if (MODE == 1) { wl0 = Wl[c0]; wl1 = Wl[c0 + 1]; }
  float ssum0 = 0.f, ssum1 = 0.f, ssq0 = 0.f, ssq1 = 0.f;
  int stride = gridDim.x * 4;
  for (int i = blockIdx.x * 4 + wv; i < NN; i += stride) {
    unsigned sv = HS[(size_t)i * HD2 + lane];
    float ax = bf_lo(sv), ay = bf_hi(sv);  // self-loop term (HS pre-scaled by dis)
    float bx = 0.f, by = 0.f;              // 4 accumulator chains
    float cx = 0.f, cy = 0.f;
    float dx = 0.f, dy = 0.f;
    int e0 = rowptr[i], e1 = rowptr[i + 1];
    int e = e0;
    // 8-edge unroll: 8 independent loads in flight before first consume
    for (; e + 7 < e1; e += 8) {
      int s0 = colidx[e];
      int s1 = colidx[e + 1];
      int s2 = colidx[e + 2];
      int s3 = colidx[e + 3];
      int s4 = colidx[e + 4];
      int s5 = colidx[e + 5];
      int s6 = colidx[e + 6];
      int s7 = colidx[e + 7];
      unsigned h0 = HS[(size_t)s0 * HD2 + lane];
      unsigned h1 = HS[(size_t)s1 * HD2 + lane];
      unsigned h2 = HS[(size_t)s2 * HD2 + lane];
      unsigned h3 = HS[(size_t)s3 * HD2 + lane];
      unsigned h4 = HS[(size_t)s4 * HD2 + lane];
      unsigned h5 = HS[(size_t)s5 * HD2 + lane];
      unsigned h6 = HS[(size_t)s6 * HD2 + lane];
      unsigned h7 = HS[(size_t)s7 * HD2 + lane];
      ax += bf_lo(h0); ay += bf_hi(h0);
      bx += bf_lo(h1); by += bf_hi(h1);
      cx += bf_lo(h2); cy += bf_hi(h2);
      dx += bf_lo(h3); dy += bf_hi(h3);
      ax += bf_lo(h4); ay += bf_hi(h4);
      bx += bf_lo(h5); by += bf_hi(h5);
      cx += bf_lo(h6); cy += bf_hi(h6);
      dx += bf_lo(h7); dy += bf_hi(h7);
    }
    for (; e + 3 < e1; e += 4) {
      int s0 = colidx[e];
      int s1 = colidx[e + 1];
      int s2 = colidx[e + 2];
      int s3 = colidx[e + 3];
      unsigned h0 = HS[(size_t)s0 * HD2 + lane];
      unsigned h1 = HS[(size_t)s1 * HD2 + lane];
      unsigned h2 = HS[(size_t)s2 * HD2 + lane];
      unsigned h3 = HS[(size_t)s3 * HD2 + lane];
      ax += bf_lo(h0); ay += bf_hi(h0);
      bx += bf_lo(h1); by += bf_hi(h1);
      cx += bf_lo(h2); cy += bf_hi(h2);
      dx += bf_lo(h3); dy += bf_hi(h3);
    }
    for (; e < e1; ++e) {
      int s0 = colidx[e];
      unsigned h0 = HS[(size_t)s0 * HD2 + lane];
      ax += bf_lo(h0); ay += bf_hi(h0);
    }
    float di = dis[i];
    float vx = fmaf(di, (ax + bx) + (cx + dx), b0);
    float vy = fmaf(di, (ay + by) + (cy + dy), b1);
    if (MODE == 0) {
      *(float2*)&AGG[(size_t)i * HD + c0] = make_float2(vx, vy);
      ssum0 += vx; ssum1 += vy;
      ssq0 = fmaf(vx, vx, ssq0);
      ssq1 = fmaf(vy, vy, ssq1);
    } else {
      vx = fmaxf(vx, 0.f);
      vy = fmaxf(vy, 0.f);
      float p = vx * wl0 + vy * wl1;
#pragma unroll
      for (int m = 32; m >= 1; m >>= 1) p += __shfl_xor(p, m);
      if (lane == 0) {
        int b = batch[i];
        atomicAdd(&gsum[b], p);
        atomicAdd(&gcnt[b], 1.0f);
      }
    }
  }
  if (MODE == 0) {
    red[wv][c0] = ssum0; red[wv][c0 + 1] = ssum1;
    __syncthreads();
    if (wv == 0) {
      float t0 = red[0][c0] + red[1][c0] + red[2][c0] + red[3][c0];
      float t1 = red[0][c0 + 1] + red[1][c0 + 1] + red[2][c0 + 1] + red[3][c0 + 1];
      atomicAdd(&stats[c0], t0);
      atomicAdd(&stats[c0 + 1], t1);
    }
    __syncthreads();
    red[wv][c0] = ssq0; red[wv][c0 + 1] = ssq1;
    __syncthreads();
    if (wv == 0) {
      float q0 = red[0][c0] + red[1][c0] + red[2][c0] + red[3][c0];
      float q1 = red[0][c0 + 1] + red[1][c0 + 1] + red[2][c0 + 1] + red[3][c0 + 1];
      atomicAdd(&stats[HD + c0], q0);
      atomicAdd(&stats[HD + c0 + 1], q1);
    }
  }
}

// ---------------- BN finalize: per-channel scale/shift ----------------
__global__ void k_bnfin(const float* __restrict__ stats, const float* __restrict__ gamma,
                        const float* __restrict__ beta, float* __restrict__ scale,
                        float* __restrict__ shift) {
  int c = threadIdx.x;
  float inv_n = 1.0f / (float)NN;
  float mean = stats[c] * inv_n;
  float var = stats[HD + c] * inv_n - mean * mean;
  float s = gamma[c] / sqrtf(var + BN_EPS);
  scale[c] = s;
  shift[c] = fmaf(-mean, s, beta[c]);
}

// ---------------- final: mean-pool divide + bias ----------------
__global__ void k_final(const float* __restrict__ gsum, const float* __restrict__ gcnt,
                        const float* __restrict__ bl, float* __restrict__ out) {
  int g = threadIdx.x;
  out[g] = gsum[g] / fmaxf(gcnt[g], 1.0f) + bl[0];
}

extern "C" void kernel_launch(void* const* d_in, const int* in_sizes, int n_in,
                              void* d_out, int out_size, void* d_ws, size_t ws_size,
                              hipStream_t stream) {
  (void)in_sizes; (void)n_in; (void)out_size; (void)ws_size;
  const float* x   = (const float*)d_in[0];
  const int* ei    = (const int*)d_in[1];
  const int* batch = (const int*)d_in[2];
  const float* W1  = (const float*)d_in[3];
  const float* b1  = (const float*)d_in[4];
  const float* g1  = (const float*)d_in[5];
  const float* be1 = (const float*)d_in[6];
  const float* W2  = (const float*)d_in[7];
  const float* b2  = (const float*)d_in[8];
  const float* g2  = (const float*)d_in[9];
  const float* be2 = (const float*)d_in[10];
  const float* W3  = (const float*)d_in[11];
  const float* b3  = (const float*)d_in[12];
  const float* Wl  = (const float*)d_in[13];
  const float* bl  = (const float*)d_in[14];
  float* out = (float*)d_out;

  const int* srcv = ei;        // edge_index[0]
  const int* dstv = ei + NE;   // edge_index[1]

  // ---- workspace layout (all offsets 16B-aligned) ----
  unsigned* hs  = (unsigned*)d_ws;            // [NN][HD2] bf16x2 packed
  float* agg    = (float*)(hs + (size_t)NN * HD2);  // [NN][HD] fp32
  float* dis    = agg + (size_t)NN * HD;      // [NN]
  int*   rowptr = (int*)(dis + NN);           // [NN+1] (padded to NN+4)
  int*   colidx = rowptr + (NN + 4);          // [NE]
  float* scale1 = (float*)(colidx + NE);
  float* shift1 = scale1 + HD;
  float* scale2 = shift1 + HD;
  float* shift2 = scale2 + HD;
  float* zbase  = shift2 + HD;                // ---- zeroed region start ----
  int*   degc   = (int*)zbase;                // [NN]
  int*   fillp  = degc + NN;                  // [NN]
  int*   aux    = fillp + NN;                 // [64]
  int*   auxsc  = aux + 64;                   // [64]
  float* stats1 = (float*)(auxsc + 64);       // [256]
  float* stats2 = stats1 + 2 * HD;            // [256]
  float* gsum   = stats2 + 2 * HD;            // [256]
  float* gcnt   = gsum + NGR;                 // [256]
  float* zend   = gcnt + NGR;
  int n4 = (int)(((char*)zend - (char*)zbase) / 16);

  k_zero<<<(n4 + 255) / 256, 256, 0, stream>>>((float4*)zbase, n4);

  // CSR build (once; reused by all 3 layers)
  k_count<<<(NE + 255) / 256, 256, 0, stream>>>(dstv, degc);
  int nchunk = (NN + 1023) / 1024;
  k_scan1<<<nchunk, 1024, 0, stream>>>(degc, rowptr, aux, dis);
  k_scan2<<<1, 1, 0, stream>>>(aux, auxsc, nchunk);
  k_scan3<<<(NN + 255) / 256, 256, 0, stream>>>(rowptr, auxsc);
  k_fill<<<(NE + 255) / 256, 256, 0, stream>>>(srcv, dstv, rowptr, fillp, colidx);

  int gblk = (NN + 63) / 64;
  // layer 1
  k_gemm<false><<<gblk, 256, 0, stream>>>(x, W1, nullptr, nullptr, dis, hs);
  k_agg<0><<<2048, 256, 0, stream>>>(hs, dis, rowptr, colidx, b1, agg, stats1,
                                     nullptr, nullptr, nullptr, nullptr);
  k_bnfin<<<1, HD, 0, stream>>>(stats1, g1, be1, scale1, shift1);
  // layer 2
  k_gemm<true><<<gblk, 256, 0, stream>>>(agg, W2, scale1, shift1, dis, hs);
  k_agg<0><<<2048, 256, 0, stream>>>(hs, dis, rowptr, colidx, b2, agg, stats2,
                                     nullptr, nullptr, nullptr, nullptr);
  k_bnfin<<<1, HD, 0, stream>>>(stats2, g2, be2, scale2, shift2);
  // layer 3 (BN+ReLU of layer2 fused into GEMM load; pool+linear fused into agg)
  k_gemm<true><<<gblk, 256, 0, stream>>>(agg, W3, scale2, shift2, dis, hs);
  k_agg<1><<<2048, 256, 0, stream>>>(hs, dis, rowptr, colidx, b3, nullptr, nullptr,
                                     batch, Wl, gsum, gcnt);
  k_final<<<1, NGR, 0, stream>>>(gsum, gcnt, bl, out);
}